// Round 1
// baseline (2061.442 us; speedup 1.0000x reference)
//
#include <hip/hip_runtime.h>
#include <math.h>
#include <limits.h>

#define QN 1024
#define NN 50000
#define DD 512
#define KNN 10
#define NT 128
#define QT 64
#define BK 32
#define NS ((NN + NT - 1) / NT)        /* 391 n-slices */
#define NROWS (NN + QN)

/* workspace layout, in 4-byte elements */
#define WS_D2 0
#define WS_X2 50176
#define WS_CD 51200
#define WS_CI (WS_CD + QN * NS * KNN)  /* 51200 + 4003840 */

__device__ __forceinline__ bool lless(float d1, int i1, float d2, int i2) {
  return (d1 < d2) || (d1 == d2 && i1 < i2);
}

/* ---------------- K1: row norms ---------------- */
__global__ __launch_bounds__(256) void norms_kernel(
    const float* __restrict__ Xm, const float* __restrict__ dat,
    float* __restrict__ ws) {
  int w = threadIdx.x >> 6, lane = threadIdx.x & 63;
  int row = blockIdx.x * 4 + w;
  if (row >= NROWS) return;
  const float* p = (row < NN) ? (dat + (size_t)row * DD)
                              : (Xm + (size_t)(row - NN) * DD);
  float s = 0.f;
#pragma unroll
  for (int i = 0; i < DD / 64; i++) {
    float v = p[lane + i * 64];
    s = fmaf(v, v, s);
  }
#pragma unroll
  for (int off = 32; off; off >>= 1) s += __shfl_down(s, off, 64);
  if (lane == 0) {
    if (row < NN) ws[WS_D2 + row] = s;
    else          ws[WS_X2 + (row - NN)] = s;
  }
}

/* ---------------- K2: tiled GEMM + fused per-slice top-10 ---------------- */
struct StageT { float a[BK][QT]; float b[BK][NT]; };
struct SelT   { float sq[32][NT + 4]; float md[32][8][KNN]; int mi[32][8][KNN]; };
union SmemT   { StageT s; SelT e; };

__global__ __launch_bounds__(256) void knn_chunk(
    const float* __restrict__ Xm, const float* __restrict__ dat,
    float* __restrict__ ws) {
  __shared__ SmemT sm;
  const int slice = blockIdx.x;          /* 0..390 */
  const int qb    = blockIdx.y;          /* 0..15  */
  const int t     = threadIdx.x;
  const int qbase = qb * QT;
  const int nbase = slice * NT;
  const int tq = t >> 5, tn = t & 31;

  float acc[8][4];
#pragma unroll
  for (int i = 0; i < 8; i++)
#pragma unroll
    for (int j = 0; j < 4; j++) acc[i][j] = 0.f;

  for (int kk = 0; kk < DD; kk += BK) {
    __syncthreads();
#pragma unroll
    for (int j = 0; j < 2; j++) {        /* stage A: 512 float4 */
      int f = t + j * 256;
      int q = f >> 3, k4 = f & 7;
      const float4 v = *(const float4*)(Xm + (size_t)(qbase + q) * DD + kk + k4 * 4);
      sm.s.a[k4 * 4 + 0][q] = v.x;
      sm.s.a[k4 * 4 + 1][q] = v.y;
      sm.s.a[k4 * 4 + 2][q] = v.z;
      sm.s.a[k4 * 4 + 3][q] = v.w;
    }
#pragma unroll
    for (int j = 0; j < 4; j++) {        /* stage B: 1024 float4 */
      int f = t + j * 256;
      int n = f >> 3, k4 = f & 7;
      int gn = nbase + n;
      float4 v = make_float4(0.f, 0.f, 0.f, 0.f);
      if (gn < NN) v = *(const float4*)(dat + (size_t)gn * DD + kk + k4 * 4);
      sm.s.b[k4 * 4 + 0][n] = v.x;
      sm.s.b[k4 * 4 + 1][n] = v.y;
      sm.s.b[k4 * 4 + 2][n] = v.z;
      sm.s.b[k4 * 4 + 3][n] = v.w;
    }
    __syncthreads();
#pragma unroll
    for (int k = 0; k < BK; k++) {
      float4 a0 = *(const float4*)&sm.s.a[k][tq * 8];
      float4 a1 = *(const float4*)&sm.s.a[k][tq * 8 + 4];
      float4 b0 = *(const float4*)&sm.s.b[k][tn * 4];
      float av[8] = {a0.x, a0.y, a0.z, a0.w, a1.x, a1.y, a1.z, a1.w};
      float bv[4] = {b0.x, b0.y, b0.z, b0.w};
#pragma unroll
      for (int i = 0; i < 8; i++)
#pragma unroll
        for (int j = 0; j < 4; j++)
          acc[i][j] = fmaf(av[i], bv[j], acc[i][j]);
    }
  }

  const float INF = __builtin_inff();

  for (int pass = 0; pass < 2; pass++) {
    __syncthreads();
    if ((tq >> 2) == pass) {             /* dump 32 rows of sq into LDS */
      float d2v[4];
      int gn[4];
#pragma unroll
      for (int j = 0; j < 4; j++) {
        gn[j] = nbase + tn * 4 + j;
        d2v[j] = (gn[j] < NN) ? ws[WS_D2 + gn[j]] : INF;
      }
#pragma unroll
      for (int i = 0; i < 8; i++) {
        int q = tq * 8 + i;
        float x2v = ws[WS_X2 + qbase + q];
        int lr = (tq & 3) * 8 + i;
#pragma unroll
        for (int j = 0; j < 4; j++) {
          float sq = (gn[j] < NN) ? (x2v + d2v[j] - 2.f * acc[i][j]) : INF;
          sm.e.sq[lr][tn * 4 + j] = sq;
        }
      }
    }
    __syncthreads();
    {                                    /* 8 members/row scan 16 cols each */
      int r = t >> 3, m = t & 7;
      float td[KNN]; int ti[KNN];
#pragma unroll
      for (int p = 0; p < KNN; p++) { td[p] = INF; ti[p] = INT_MAX; }
      for (int c = m * 16; c < m * 16 + 16; c++) {
        float v = sm.e.sq[r][c];
        int idx = nbase + c;
        if (lless(v, idx, td[KNN - 1], ti[KNN - 1])) {
          float cd = v; int cidx = idx;
#pragma unroll
          for (int p = 0; p < KNN; p++) {
            if (lless(cd, cidx, td[p], ti[p])) {
              float tmpd = td[p]; td[p] = cd; cd = tmpd;
              int tmpi = ti[p]; ti[p] = cidx; cidx = tmpi;
            }
          }
        }
      }
#pragma unroll
      for (int p = 0; p < KNN; p++) { sm.e.md[r][m][p] = td[p]; sm.e.mi[r][m][p] = ti[p]; }
    }
    __syncthreads();
    {                                    /* member 0: 8-way stable merge */
      int r = t >> 3, m = t & 7;
      if (m == 0) {
        int qg = qbase + pass * 32 + r;
        float* outd = ws + WS_CD + ((size_t)qg * NS + slice) * KNN;
        int*   outi = ((int*)ws) + WS_CI + ((size_t)qg * NS + slice) * KNN;
        int hp[8] = {0, 0, 0, 0, 0, 0, 0, 0};
        for (int pick = 0; pick < KNN; pick++) {
          float bd = 0.f; int bi = 0; int bm = -1;
          for (int mm = 0; mm < 8; mm++) {
            if (hp[mm] >= KNN) continue;
            float hd = sm.e.md[r][mm][hp[mm]];
            int   hi = sm.e.mi[r][mm][hp[mm]];
            if (bm < 0 || lless(hd, hi, bd, bi)) { bd = hd; bi = hi; bm = mm; }
          }
          outd[pick] = bd; outi[pick] = bi; hp[bm]++;
        }
      }
    }
  }
}

/* ---------------- K3: per-query final merge + mode ---------------- */
__global__ __launch_bounds__(64) void knn_final(
    const int* __restrict__ targets, float* __restrict__ ws,
    float* __restrict__ out) {
  const int q = blockIdx.x;
  const int t = threadIdx.x;
  const float INF = __builtin_inff();
  const float* cd = ws + WS_CD + (size_t)q * NS * KNN;
  const int*   ci = ((const int*)ws) + WS_CI + (size_t)q * NS * KNN;
  const int NC = NS * KNN;

  float td[KNN]; int ti[KNN];
#pragma unroll
  for (int p = 0; p < KNN; p++) { td[p] = INF; ti[p] = INT_MAX; }
  for (int j = t; j < NC; j += 64) {
    float d = cd[j]; int i = ci[j];
    if (lless(d, i, td[KNN - 1], ti[KNN - 1])) {
      float c0 = d; int c1 = i;
#pragma unroll
      for (int p = 0; p < KNN; p++) {
        if (lless(c0, c1, td[p], ti[p])) {
          float tmpd = td[p]; td[p] = c0; c0 = tmpd;
          int tmpi = ti[p]; ti[p] = c1; c1 = tmpi;
        }
      }
    }
  }

  __shared__ float wd[64][KNN]; __shared__ int wi[64][KNN];
  __shared__ float m2d[8][KNN]; __shared__ int m2i[8][KNN];
#pragma unroll
  for (int p = 0; p < KNN; p++) { wd[t][p] = td[p]; wi[t][p] = ti[p]; }
  __syncthreads();
  if (t < 8) {
    int hp[8] = {0, 0, 0, 0, 0, 0, 0, 0};
    for (int pick = 0; pick < KNN; pick++) {
      float bd = 0.f; int bi = 0; int bm = -1;
      for (int mm = 0; mm < 8; mm++) {
        if (hp[mm] >= KNN) continue;
        int lid = t * 8 + mm;
        float hd = wd[lid][hp[mm]]; int hi = wi[lid][hp[mm]];
        if (bm < 0 || lless(hd, hi, bd, bi)) { bd = hd; bi = hi; bm = mm; }
      }
      m2d[t][pick] = bd; m2i[t][pick] = bi; hp[bm]++;
    }
  }
  __syncthreads();
  if (t == 0) {
    int hp[8] = {0, 0, 0, 0, 0, 0, 0, 0};
    int fi[KNN];
    for (int pick = 0; pick < KNN; pick++) {
      float bd = 0.f; int bi = 0; int bm = -1;
      for (int mm = 0; mm < 8; mm++) {
        if (hp[mm] >= KNN) continue;
        float hd = m2d[mm][hp[mm]]; int hi = m2i[mm][hp[mm]];
        if (bm < 0 || lless(hd, hi, bd, bi)) { bd = hd; bi = hi; bm = mm; }
      }
      fi[pick] = bi; hp[bm]++;
    }
    int lab[KNN];
#pragma unroll
    for (int p = 0; p < KNN; p++) lab[p] = targets[fi[p]];
    int bc = 0, bl = INT_MAX;
#pragma unroll
    for (int i = 0; i < KNN; i++) {
      int c = 0;
#pragma unroll
      for (int j = 0; j < KNN; j++) c += (lab[j] == lab[i]) ? 1 : 0;
      if (c > bc || (c == bc && lab[i] < bl)) { bc = c; bl = lab[i]; }
    }
    out[q] = (float)bl;
  }
}

extern "C" void kernel_launch(void* const* d_in, const int* in_sizes, int n_in,
                              void* d_out, int out_size, void* d_ws, size_t ws_size,
                              hipStream_t stream) {
  const float* Xm  = (const float*)d_in[0];
  const float* dat = (const float*)d_in[1];
  const int* targets = (const int*)d_in[2];
  float* out = (float*)d_out;
  float* ws  = (float*)d_ws;

  hipLaunchKernelGGL(norms_kernel, dim3((NROWS + 3) / 4), dim3(256), 0, stream,
                     Xm, dat, ws);
  hipLaunchKernelGGL(knn_chunk, dim3(NS, QN / QT), dim3(256), 0, stream,
                     Xm, dat, ws);
  hipLaunchKernelGGL(knn_final, dim3(QN), dim3(64), 0, stream,
                     targets, ws, out);
}

// Round 2
// 1058.176 us; speedup vs baseline: 1.9481x; 1.9481x over previous
//
#include <hip/hip_runtime.h>
#include <math.h>
#include <limits.h>

#define QN 1024
#define NN 50000
#define NPAD 50048
#define DD 512
#define KNN 10
#define NT 128            /* data points per block  */
#define QTB 128           /* queries per block      */
#define BK 32             /* k-chunk                */
#define NS 391            /* ceil(50000/128)        */
#define QB 8              /* 1024/128               */

/* workspace layout, in 4-byte elements */
#define WS_D2 0
#define WS_CD NPAD
#define WS_CI (WS_CD + QN * NS * KNN)

typedef __attribute__((ext_vector_type(8))) short short8;  /* 8 bf16 = 4 VGPR */
typedef __attribute__((ext_vector_type(4))) float f32x4;

#define PANEL_B 1152      /* 64 chunks * 16B + 8 * 16B pad; 288 words = 9*32 */
#define REGION_B (8 * PANEL_B)

__device__ __forceinline__ bool lless(float d1, int i1, float d2, int i2) {
  return (d1 < d2) || (d1 == d2 && i1 < i2);
}

/* split 2 floats into packed bf16 hi-pair and lo-pair words (RNE) */
__device__ __forceinline__ void cvt2(float x, float y, unsigned& hi, unsigned& lo) {
  unsigned ux = __float_as_uint(x), uy = __float_as_uint(y);
  unsigned rx = ux + 0x7fffu + ((ux >> 16) & 1u);
  unsigned ry = uy + 0x7fffu + ((uy >> 16) & 1u);
  hi = (rx >> 16) | (ry & 0xffff0000u);
  float xl = x - __uint_as_float(rx & 0xffff0000u);
  float yl = y - __uint_as_float(ry & 0xffff0000u);
  unsigned uxl = __float_as_uint(xl), uyl = __float_as_uint(yl);
  unsigned rxl = uxl + 0x7fffu + ((uxl >> 16) & 1u);
  unsigned ryl = uyl + 0x7fffu + ((uyl >> 16) & 1u);
  lo = (rxl >> 16) | (ryl & 0xffff0000u);
}

/* ---------------- K1: data row norms (padded with +inf) ---------------- */
__global__ __launch_bounds__(256) void norms_kernel(
    const float* __restrict__ dat, float* __restrict__ ws) {
  int w = threadIdx.x >> 6, lane = threadIdx.x & 63;
  int row = blockIdx.x * 4 + w;
  if (row >= NPAD) return;
  if (row >= NN) {
    if (lane == 0) ws[WS_D2 + row] = __builtin_inff();
    return;
  }
  const float4* p = (const float4*)(dat + (size_t)row * DD);
  float s = 0.f;
#pragma unroll
  for (int i = 0; i < 2; i++) {
    float4 v = p[lane + i * 64];
    s = fmaf(v.x, v.x, s); s = fmaf(v.y, v.y, s);
    s = fmaf(v.z, v.z, s); s = fmaf(v.w, v.w, s);
  }
#pragma unroll
  for (int off = 32; off; off >>= 1) s += __shfl_down(s, off, 64);
  if (lane == 0) ws[WS_D2 + row] = s;
}

/* ---------------- K2: split-bf16 MFMA GEMM + fused per-slice top-10 ----- */
struct EpiT {
  float sq[32][132];
  float md[32][8][KNN];
  int   mi[32][8][KNN];
};
union SmemU {
  unsigned char stage[4 * REGION_B];  /* AH | AL | BH | BL */
  EpiT e;
};

__global__ __launch_bounds__(256, 2) void knn_chunk(
    const float* __restrict__ Xm, const float* __restrict__ dat,
    float* __restrict__ ws) {
  __shared__ __align__(16) SmemU sm;
  const int qbase = blockIdx.x * QTB;
  const int nbase = blockIdx.y * NT;
  const int t = threadIdx.x;
  const int lane = t & 63, wave = t >> 6;
  const int wn = wave & 1, wq = wave >> 1;

  f32x4 acc[4][4];
#pragma unroll
  for (int i = 0; i < 4; i++)
#pragma unroll
    for (int j = 0; j < 4; j++) acc[i][j] = (f32x4)0.f;

  /* lane-linear fragment offset within a panel (16B pad every 8 chunks) */
  const int fragoff = lane * 16 + ((lane >> 3) << 4);

  for (int kk = 0; kk < DD; kk += BK) {
    __syncthreads();
#pragma unroll
    for (int it = 0; it < 2; it++) {   /* 512 8-k chunk positions per side */
      int cp = t + it * 256;
      int row = cp >> 2, quad = cp & 3;
      int c = (quad << 4) | (row & 15);
      int off = (row >> 4) * PANEL_B + c * 16 + ((c >> 3) << 4);
      { /* A side: X queries */
        const float* src = Xm + (size_t)(qbase + row) * DD + kk + quad * 8;
        float4 v0 = *(const float4*)src;
        float4 v1 = *(const float4*)(src + 4);
        unsigned h0, h1, h2, h3, l0, l1, l2, l3;
        cvt2(v0.x, v0.y, h0, l0); cvt2(v0.z, v0.w, h1, l1);
        cvt2(v1.x, v1.y, h2, l2); cvt2(v1.z, v1.w, h3, l3);
        *(uint4*)(sm.stage + off)            = make_uint4(h0, h1, h2, h3);
        *(uint4*)(sm.stage + REGION_B + off) = make_uint4(l0, l1, l2, l3);
      }
      { /* B side: data points (zero-pad OOB rows) */
        int gr = nbase + row;
        float4 v0 = make_float4(0.f, 0.f, 0.f, 0.f), v1 = v0;
        if (gr < NN) {
          const float* src = dat + (size_t)gr * DD + kk + quad * 8;
          v0 = *(const float4*)src; v1 = *(const float4*)(src + 4);
        }
        unsigned h0, h1, h2, h3, l0, l1, l2, l3;
        cvt2(v0.x, v0.y, h0, l0); cvt2(v0.z, v0.w, h1, l1);
        cvt2(v1.x, v1.y, h2, l2); cvt2(v1.z, v1.w, h3, l3);
        *(uint4*)(sm.stage + 2 * REGION_B + off) = make_uint4(h0, h1, h2, h3);
        *(uint4*)(sm.stage + 3 * REGION_B + off) = make_uint4(l0, l1, l2, l3);
      }
    }
    __syncthreads();

    short8 ah[4], al_[4], bh[4], bl_[4];
#pragma unroll
    for (int i = 0; i < 4; i++) {
      ah[i]  = *(const short8*)(sm.stage + (wq * 4 + i) * PANEL_B + fragoff);
      al_[i] = *(const short8*)(sm.stage + REGION_B + (wq * 4 + i) * PANEL_B + fragoff);
      bh[i]  = *(const short8*)(sm.stage + 2 * REGION_B + (wn * 4 + i) * PANEL_B + fragoff);
      bl_[i] = *(const short8*)(sm.stage + 3 * REGION_B + (wn * 4 + i) * PANEL_B + fragoff);
    }
#pragma unroll
    for (int mt = 0; mt < 4; mt++)
#pragma unroll
      for (int nt = 0; nt < 4; nt++) {
        acc[mt][nt] = __builtin_amdgcn_mfma_f32_16x16x32_bf16(ah[mt],  bh[nt],  acc[mt][nt], 0, 0, 0);
        acc[mt][nt] = __builtin_amdgcn_mfma_f32_16x16x32_bf16(ah[mt],  bl_[nt], acc[mt][nt], 0, 0, 0);
        acc[mt][nt] = __builtin_amdgcn_mfma_f32_16x16x32_bf16(al_[mt], bh[nt],  acc[mt][nt], 0, 0, 0);
      }
  }

  /* ---- epilogue: key = d2 - 2*dot (x2 constant per query), top-10/slice */
  const float INF = __builtin_inff();
  for (int p = 0; p < 4; p++) {
    __syncthreads();
    if (wq == (p >> 1)) {
      int tq0 = (p & 1) * 2;
#pragma unroll
      for (int tt = 0; tt < 2; tt++) {
        int tq = tq0 + tt;
#pragma unroll
        for (int nt = 0; nt < 4; nt++) {
          int nl = wn * 64 + nt * 16 + (lane & 15);
          float d2v = ws[WS_D2 + nbase + nl];
#pragma unroll
          for (int rg = 0; rg < 4; rg++) {
            int qp = tt * 16 + (lane >> 4) * 4 + rg;
            sm.e.sq[qp][nl] = fmaf(-2.f, acc[tq][nt][rg], d2v);
          }
        }
      }
    }
    __syncthreads();
    {
      int r = t >> 3, mm = t & 7;
      float td[KNN]; int ti[KNN];
#pragma unroll
      for (int u = 0; u < KNN; u++) { td[u] = INF; ti[u] = INT_MAX; }
      for (int it = 0; it < 16; it++) {
        int cc = it * 8 + mm;              /* stride-8 scan: <=2-way banks */
        float v = sm.e.sq[r][cc];
        int idx = nbase + cc;
        if (lless(v, idx, td[KNN - 1], ti[KNN - 1])) {
          float cd = v; int cidx = idx;
#pragma unroll
          for (int u = 0; u < KNN; u++) {
            if (lless(cd, cidx, td[u], ti[u])) {
              float tmpd = td[u]; td[u] = cd; cd = tmpd;
              int tmpi = ti[u]; ti[u] = cidx; cidx = tmpi;
            }
          }
        }
      }
#pragma unroll
      for (int u = 0; u < KNN; u++) { sm.e.md[r][mm][u] = td[u]; sm.e.mi[r][mm][u] = ti[u]; }
    }
    __syncthreads();
    if ((t & 7) == 0) {                    /* stable 8-way merge, 1 thr/row */
      int r = t >> 3;
      int qg = qbase + p * 32 + r;
      float* outd = ws + WS_CD + ((size_t)qg * NS + blockIdx.y) * KNN;
      int*   outi = ((int*)ws) + WS_CI + ((size_t)qg * NS + blockIdx.y) * KNN;
      int hp[8] = {0, 0, 0, 0, 0, 0, 0, 0};
      for (int pick = 0; pick < KNN; pick++) {
        float bd = 0.f; int bi = 0; int bm = -1;
        for (int m2 = 0; m2 < 8; m2++) {
          if (hp[m2] >= KNN) continue;
          float hd = sm.e.md[r][m2][hp[m2]];
          int   hi = sm.e.mi[r][m2][hp[m2]];
          if (bm < 0 || lless(hd, hi, bd, bi)) { bd = hd; bi = hi; bm = m2; }
        }
        outd[pick] = bd; outi[pick] = bi; hp[bm]++;
      }
    }
  }
}

/* ---------------- K3: per-query final merge + mode ---------------- */
__global__ __launch_bounds__(64) void knn_final(
    const int* __restrict__ targets, float* __restrict__ ws,
    float* __restrict__ out) {
  const int q = blockIdx.x;
  const int t = threadIdx.x;
  const float INF = __builtin_inff();
  const float* cd = ws + WS_CD + (size_t)q * NS * KNN;
  const int*   ci = ((const int*)ws) + WS_CI + (size_t)q * NS * KNN;
  const int NC = NS * KNN;

  float td[KNN]; int ti[KNN];
#pragma unroll
  for (int u = 0; u < KNN; u++) { td[u] = INF; ti[u] = INT_MAX; }
  for (int j = t; j < NC; j += 64) {
    float d = cd[j]; int i = ci[j];
    if (lless(d, i, td[KNN - 1], ti[KNN - 1])) {
      float c0 = d; int c1 = i;
#pragma unroll
      for (int u = 0; u < KNN; u++) {
        if (lless(c0, c1, td[u], ti[u])) {
          float tmpd = td[u]; td[u] = c0; c0 = tmpd;
          int tmpi = ti[u]; ti[u] = c1; c1 = tmpi;
        }
      }
    }
  }

  __shared__ float wd[64][KNN]; __shared__ int wi[64][KNN];
  __shared__ float m2d[8][KNN]; __shared__ int m2i[8][KNN];
#pragma unroll
  for (int u = 0; u < KNN; u++) { wd[t][u] = td[u]; wi[t][u] = ti[u]; }
  __syncthreads();
  if (t < 8) {
    int hp[8] = {0, 0, 0, 0, 0, 0, 0, 0};
    for (int pick = 0; pick < KNN; pick++) {
      float bd = 0.f; int bi = 0; int bm = -1;
      for (int mm = 0; mm < 8; mm++) {
        if (hp[mm] >= KNN) continue;
        int lid = t * 8 + mm;
        float hd = wd[lid][hp[mm]]; int hi = wi[lid][hp[mm]];
        if (bm < 0 || lless(hd, hi, bd, bi)) { bd = hd; bi = hi; bm = mm; }
      }
      m2d[t][pick] = bd; m2i[t][pick] = bi; hp[bm]++;
    }
  }
  __syncthreads();
  if (t == 0) {
    int hp[8] = {0, 0, 0, 0, 0, 0, 0, 0};
    int fi[KNN];
    for (int pick = 0; pick < KNN; pick++) {
      float bd = 0.f; int bi = 0; int bm = -1;
      for (int mm = 0; mm < 8; mm++) {
        if (hp[mm] >= KNN) continue;
        float hd = m2d[mm][hp[mm]]; int hi = m2i[mm][hp[mm]];
        if (bm < 0 || lless(hd, hi, bd, bi)) { bd = hd; bi = hi; bm = mm; }
      }
      fi[pick] = bi; hp[bm]++;
    }
    int lab[KNN];
#pragma unroll
    for (int u = 0; u < KNN; u++) lab[u] = targets[fi[u]];
    int bc = 0, bl = INT_MAX;
#pragma unroll
    for (int i = 0; i < KNN; i++) {
      int c = 0;
#pragma unroll
      for (int j = 0; j < KNN; j++) c += (lab[j] == lab[i]) ? 1 : 0;
      if (c > bc || (c == bc && lab[i] < bl)) { bc = c; bl = lab[i]; }
    }
    out[q] = (float)bl;
  }
}

extern "C" void kernel_launch(void* const* d_in, const int* in_sizes, int n_in,
                              void* d_out, int out_size, void* d_ws, size_t ws_size,
                              hipStream_t stream) {
  const float* Xm  = (const float*)d_in[0];
  const float* dat = (const float*)d_in[1];
  const int* targets = (const int*)d_in[2];
  float* out = (float*)d_out;
  float* ws  = (float*)d_ws;

  hipLaunchKernelGGL(norms_kernel, dim3(NPAD / 4), dim3(256), 0, stream, dat, ws);
  hipLaunchKernelGGL(knn_chunk, dim3(QB, NS), dim3(256), 0, stream, Xm, dat, ws);
  hipLaunchKernelGGL(knn_final, dim3(QN), dim3(64), 0, stream, targets, ws, out);
}